// Round 1
// baseline (52.009 us; speedup 1.0000x reference)
//
#include <hip/hip_runtime.h>
#include <math.h>

// Tropical (min-plus) linear layer:
//   out[b, o] = min_i ( X[b, i] + W[o, i] )
// B=1024, I=512, O=512, all fp32.
//
// Pure VALU problem (no MFMA for min-plus semiring).
// Scheme: lane <-> o (coalesced W-read-from-LDS + coalesced stores),
//         X via wave-uniform loads (-> s_load, SGPR operand of v_add),
//         min3 fusion: acc = min3(c0, c1, acc).

#define B_SZ   1024
#define I_F    512
#define O_F    512
#define MB     32      // batch rows per block (8 per wave x 4 waves)
#define OT     64      // out cols per block (== lanes per wave)
#define BK     32      // K chunk staged in LDS
#define NTHR   256
#define MW     8       // batch rows per wave

__global__ __launch_bounds__(NTHR, 1)
void tropical_minplus(const float* __restrict__ X,
                      const float* __restrict__ W,
                      float* __restrict__ out) {
  // W chunk, transposed: Ws4[i4][o], padded stride 65 float4 (bank-conflict-free)
  __shared__ float4 Ws4[(BK / 4) * 65];

  const int tid    = threadIdx.x;
  const int lane_o = tid & (OT - 1);   // 0..63 : output column within tile
  const int bgrp   = tid >> 6;         // 0..3  : which 8-row batch group (per wave)
  const int bid    = blockIdx.x;
  const int obt    = bid & 7;          // o-tile index (O_F / OT = 8)
  const int bb     = bid >> 3;         // b-tile index (B_SZ / MB = 32)
  const int o_base = obt * OT;
  const int b0     = bb * MB + bgrp * MW;  // this wave's first batch row

  const float4* __restrict__ Wv4 = reinterpret_cast<const float4*>(W);
  const float4* __restrict__ Xv4 = reinterpret_cast<const float4*>(X);

  float acc[MW];
#pragma unroll
  for (int m = 0; m < MW; ++m) acc[m] = __builtin_inff();

  for (int c = 0; c < I_F / BK; ++c) {
    __syncthreads();  // previous chunk's readers done before overwrite
    // Stage W chunk: OT rows x BK cols = 512 float4, 2 rounds of 256 threads.
#pragma unroll
    for (int r = 0; r < (OT * BK / 4) / NTHR; ++r) {
      int f   = r * NTHR + tid;   // 0..511
      int o_r = f >> 3;           // 0..63  (8 float4 per row)
      int c4  = f & 7;            // 0..7
      Ws4[c4 * 65 + o_r] =
          Wv4[(size_t)(o_base + o_r) * (I_F / 4) + c * (BK / 4) + c4];
    }
    __syncthreads();

#pragma unroll
    for (int i4 = 0; i4 < BK / 4; ++i4) {
      const float4 w4 = Ws4[i4 * 65 + lane_o];   // ds_read_b128, conflict-free
#pragma unroll
      for (int m = 0; m < MW; ++m) {
        // Wave-uniform address -> s_load_dwordx4; X values live in SGPRs.
        const float4 x4 = Xv4[(size_t)(b0 + m) * (I_F / 4) + c * (BK / 4) + i4];
        float c0 = x4.x + w4.x;
        float c1 = x4.y + w4.y;
        float c2 = x4.z + w4.z;
        float c3 = x4.w + w4.w;
        acc[m] = fminf(fminf(c0, c1), acc[m]);   // -> v_min3_f32
        acc[m] = fminf(fminf(c2, c3), acc[m]);   // -> v_min3_f32
      }
    }
  }

#pragma unroll
  for (int m = 0; m < MW; ++m) {
    out[(size_t)(b0 + m) * O_F + o_base + lane_o] = acc[m];  // coalesced
  }
}

extern "C" void kernel_launch(void* const* d_in, const int* in_sizes, int n_in,
                              void* d_out, int out_size, void* d_ws, size_t ws_size,
                              hipStream_t stream) {
  const float* X = (const float*)d_in[0];
  const float* W = (const float*)d_in[1];
  float* out    = (float*)d_out;

  dim3 grid(256), block(NTHR);
  hipLaunchKernelGGL(tropical_minplus, grid, block, 0, stream, X, W, out);
}

// Round 2
// 35.066 us; speedup vs baseline: 1.4832x; 1.4832x over previous
//
#include <hip/hip_runtime.h>
#include <math.h>

// Tropical (min-plus) linear: out[b,o] = min_i(X[b,i] + W[o,i])
// B=1024, I=512, O=512 fp32. Pure-VALU problem (no min-plus MFMA).
//
// Round-2 design:
//  - K-split (KS segments) for occupancy: grid = 256*KS blocks, partials in ws,
//    second kernel min-reduces.  KS chosen from ws_size (4 -> 2 -> 1 fallback).
//  - Block tile: 256 o (== tid) x 8 b x kseg.  X addresses depend only on
//    blockIdx + loop constants -> block-uniform -> scalarizable (s_load).
//  - W staged via global_load_lds width=16 (no VGPR round-trip, no ds_writes).
//    LDS layout linear [o][k4] with XOR-preswizzled SOURCE column so the
//    strided ds_read_b128 (lane stride 128B) is bank-conflict-free:
//      LDS[o][j] holds W[o][ j ^ (o&7) ]  =>  read col i4 at j = i4 ^ (o&7).
//  - acc = min3(c0,c1,acc) pairs -> v_min3_f32.

#define I_F   512
#define O_F   512
#define B_SZ  1024
#define OTILE 256            // o columns per block (== blockDim.x)
#define MB    8              // batch rows per block
#define BK    32             // k per LDS chunk
#define NTHR  256
#define BO    (B_SZ * O_F)   // 524288 outputs

__global__ __launch_bounds__(NTHR, 4)
void tropical_main(const float* __restrict__ X,
                   const float* __restrict__ W,
                   float* __restrict__ dst,   // ws (KS>1) or out (KS==1)
                   int kseg) {
  __shared__ float4 Ws4[OTILE * (BK / 4)];   // 32 KB, linear [o][k4(swizzled)]

  const int tid  = threadIdx.x;
  const int bid  = blockIdx.x;
  const int kidx = bid >> 8;        // 256 blocks per k-segment
  const int rem  = bid & 255;
  const int obt  = rem & 1;         // 2 o-tiles
  const int bb   = rem >> 1;        // 128 b-tiles
  const int o0   = obt * OTILE;
  const int b0   = bb * MB;         // block-uniform batch base
  const int k0   = kidx * kseg;

  const int wv   = tid >> 6;        // wave id 0..3
  const int lane = tid & 63;
  const int s    = tid & 7;         // read-side XOR swizzle key

  const float4* __restrict__ Wv4 = reinterpret_cast<const float4*>(W);
  const float4* __restrict__ Xv4 = reinterpret_cast<const float4*>(X);

  float acc[MB];
#pragma unroll
  for (int m = 0; m < MB; ++m) acc[m] = __builtin_inff();

  const int nchunk = kseg / BK;
  for (int c = 0; c < nchunk; ++c) {
    const int c4base = (k0 + c * BK) >> 2;   // chunk col base, float4 units

    __syncthreads();  // previous chunk's readers done
    // Stage W chunk: 256 o x 32 k = 32KB via 8 global_load_lds per wave.
    // Wave-uniform LDS base + lane*16; per-lane PRE-SWIZZLED global source.
#pragma unroll
    for (int it = 0; it < 8; ++it) {
      const int slot0 = (wv * 8 + it) * 64;        // wave-uniform LDS float4 slot
      const int f     = slot0 + lane;              // 0..2047
      const int o_r   = f >> 3;                    // dest row (o)
      const int j     = f & 7;                     // dest col slot
      const int csw   = j ^ (o_r & 7);             // source column (inverse swz)
      const float4* src = &Wv4[(size_t)(o0 + o_r) * (I_F / 4) + c4base + csw];
      __builtin_amdgcn_global_load_lds(
          (const __attribute__((address_space(1))) void*)src,
          (__attribute__((address_space(3))) void*)&Ws4[slot0],
          16, 0, 0);
    }
    __syncthreads();  // drains vmcnt -> chunk ready

#pragma unroll
    for (int i4 = 0; i4 < BK / 4; ++i4) {
      const float4 w4 = Ws4[(tid << 3) + (i4 ^ s)];  // conflict-free b128
#pragma unroll
      for (int m = 0; m < MB; ++m) {
        // Block-uniform address -> scalar load; X value is an SGPR operand.
        const float4 x4 = Xv4[(size_t)(b0 + m) * (I_F / 4) + c4base + i4];
        float c0 = x4.x + w4.x;
        float c1 = x4.y + w4.y;
        float c2 = x4.z + w4.z;
        float c3 = x4.w + w4.w;
        acc[m] = fminf(fminf(c0, c1), acc[m]);   // v_min3_f32
        acc[m] = fminf(fminf(c2, c3), acc[m]);   // v_min3_f32
      }
    }
  }

  float* o = dst + (size_t)kidx * BO;
#pragma unroll
  for (int m = 0; m < MB; ++m)
    o[(size_t)(b0 + m) * O_F + o0 + tid] = acc[m];   // coalesced
}

__global__ __launch_bounds__(NTHR, 8)
void tropical_reduce(const float4* __restrict__ ws,
                     float4* __restrict__ out, int KS) {
  const int t = blockIdx.x * NTHR + threadIdx.x;     // < BO/4
  float4 a = ws[t];
  for (int k = 1; k < KS; ++k) {
    const float4 b = ws[(size_t)k * (BO / 4) + t];
    a.x = fminf(a.x, b.x);
    a.y = fminf(a.y, b.y);
    a.z = fminf(a.z, b.z);
    a.w = fminf(a.w, b.w);
  }
  out[t] = a;
}

extern "C" void kernel_launch(void* const* d_in, const int* in_sizes, int n_in,
                              void* d_out, int out_size, void* d_ws, size_t ws_size,
                              hipStream_t stream) {
  const float* X = (const float*)d_in[0];
  const float* W = (const float*)d_in[1];
  float* out     = (float*)d_out;

  // Pick largest K-split whose partial buffer fits in ws.
  int KS = 1;
  if (ws_size >= (size_t)4 * BO * sizeof(float))      KS = 4;
  else if (ws_size >= (size_t)2 * BO * sizeof(float)) KS = 2;

  float* dst = (KS > 1) ? (float*)d_ws : out;
  const int kseg = I_F / KS;

  hipLaunchKernelGGL(tropical_main, dim3(256 * KS), dim3(NTHR), 0, stream,
                     X, W, dst, kseg);
  if (KS > 1) {
    hipLaunchKernelGGL(tropical_reduce, dim3(BO / 4 / NTHR), dim3(NTHR), 0,
                       stream, (const float4*)d_ws, (float4*)out, KS);
  }
}

// Round 3
// 31.093 us; speedup vs baseline: 1.6727x; 1.1278x over previous
//
#include <hip/hip_runtime.h>
#include <math.h>

// Tropical (min-plus) linear: out[b,o] = min_i(X[b,i] + W[o,i])
// B=1024, I=512, O=512 fp32. Pure-VALU problem (no min-plus MFMA).
//
// Round-3 design (changes vs round 2 marked *):
//  - K-split KS=4: grid 1024, 4 blocks/CU, partials min-reduced by 2nd kernel.
//  - Block tile: 256 o (== tid) x 8 b x 128 k.
//  * X read through CONSTANT address space (AS 4): uniform address + invariant
//    memory -> backend emits s_load_dwordx4. X values live in SGPRs and feed
//    v_add_f32 directly as scalar operands (no VMEM latency, no VGPRs, no LDS).
//  - W staged via global_load_lds width=16, LDS linear [o][k4] with XOR
//    pre-swizzled SOURCE column; strided ds_read_b128 is bank-conflict-free.
//  - acc = min3(c0,c1,acc) pairs -> v_min3_f32.

#define I_F   512
#define O_F   512
#define B_SZ  1024
#define OTILE 256            // o columns per block (== blockDim.x)
#define MB    8              // batch rows per block
#define BK    32             // k per LDS chunk
#define NTHR  256
#define BO    (B_SZ * O_F)   // 524288 outputs

typedef __attribute__((ext_vector_type(4))) float f32x4;
typedef const __attribute__((address_space(4))) f32x4* cx4p;   // constant-AS ptr

__global__ __launch_bounds__(NTHR, 4)
void tropical_main(const float* __restrict__ X,
                   const float* __restrict__ W,
                   float* __restrict__ dst,   // ws (KS>1) or out (KS==1)
                   int kseg) {
  __shared__ f32x4 Ws4[OTILE * (BK / 4)];   // 32 KB, linear [o][k4(swizzled)]

  const int tid  = threadIdx.x;
  const int bid  = blockIdx.x;
  const int kidx = bid >> 8;        // 256 blocks per k-segment
  const int rem  = bid & 255;
  const int obt  = rem & 1;         // 2 o-tiles
  const int bb   = rem >> 1;        // 128 b-tiles
  const int o0   = obt * OTILE;
  const int b0   = bb * MB;         // block-uniform batch base
  const int k0   = kidx * kseg;

  const int wv   = tid >> 6;        // wave id 0..3
  const int lane = tid & 63;
  const int s    = tid & 7;         // read-side XOR swizzle key

  const f32x4* __restrict__ Wv4 = reinterpret_cast<const f32x4*>(W);
  // Constant-AS view of X (same memory; flat->constant is a value-preserving cast).
  cx4p Xc = (cx4p)(unsigned long long)X;

  float acc[MB];
#pragma unroll
  for (int m = 0; m < MB; ++m) acc[m] = __builtin_inff();

  const int nchunk = kseg / BK;
  for (int c = 0; c < nchunk; ++c) {
    const int c4base = (k0 + c * BK) >> 2;   // chunk col base, float4 units

    __syncthreads();  // previous chunk's readers done
    // Stage W chunk: 256 o x 32 k = 32KB via 8 global_load_lds per wave.
    // Wave-uniform LDS base + lane*16; per-lane PRE-SWIZZLED global source.
#pragma unroll
    for (int it = 0; it < 8; ++it) {
      const int slot0 = (wv * 8 + it) * 64;        // wave-uniform LDS f32x4 slot
      const int f     = slot0 + lane;              // 0..2047
      const int o_r   = f >> 3;                    // dest row (o)
      const int j     = f & 7;                     // dest col slot
      const int csw   = j ^ (o_r & 7);             // source column (inverse swz)
      const f32x4* src = &Wv4[(size_t)(o0 + o_r) * (I_F / 4) + c4base + csw];
      __builtin_amdgcn_global_load_lds(
          (const __attribute__((address_space(1))) void*)src,
          (__attribute__((address_space(3))) void*)&Ws4[slot0],
          16, 0, 0);
    }
    __syncthreads();  // drains vmcnt -> chunk ready

#pragma unroll
    for (int i4 = 0; i4 < BK / 4; ++i4) {
      const f32x4 w4 = Ws4[(tid << 3) + (i4 ^ s)];  // conflict-free ds_read_b128
#pragma unroll
      for (int m = 0; m < MB; ++m) {
        // Uniform constant-AS load -> s_load_dwordx4; X values are SGPRs.
        const f32x4 x4 = Xc[(size_t)(b0 + m) * (I_F / 4) + c4base + i4];
        float c0 = x4.x + w4.x;    // v_add_f32 v, s, v
        float c1 = x4.y + w4.y;
        float c2 = x4.z + w4.z;
        float c3 = x4.w + w4.w;
        acc[m] = fminf(fminf(c0, c1), acc[m]);   // v_min3_f32
        acc[m] = fminf(fminf(c2, c3), acc[m]);   // v_min3_f32
      }
    }
  }

  float* o = dst + (size_t)kidx * BO;
#pragma unroll
  for (int m = 0; m < MB; ++m)
    o[(size_t)(b0 + m) * O_F + o0 + tid] = acc[m];   // coalesced
}

__global__ __launch_bounds__(NTHR, 8)
void tropical_reduce(const float4* __restrict__ ws,
                     float4* __restrict__ out, int KS) {
  const int t = blockIdx.x * NTHR + threadIdx.x;     // < BO/4
  float4 a = ws[t];
  for (int k = 1; k < KS; ++k) {
    const float4 b = ws[(size_t)k * (BO / 4) + t];
    a.x = fminf(a.x, b.x);
    a.y = fminf(a.y, b.y);
    a.z = fminf(a.z, b.z);
    a.w = fminf(a.w, b.w);
  }
  out[t] = a;
}

extern "C" void kernel_launch(void* const* d_in, const int* in_sizes, int n_in,
                              void* d_out, int out_size, void* d_ws, size_t ws_size,
                              hipStream_t stream) {
  const float* X = (const float*)d_in[0];
  const float* W = (const float*)d_in[1];
  float* out     = (float*)d_out;

  // Pick largest K-split whose partial buffer fits in ws.
  int KS = 1;
  if (ws_size >= (size_t)4 * BO * sizeof(float))      KS = 4;
  else if (ws_size >= (size_t)2 * BO * sizeof(float)) KS = 2;

  float* dst = (KS > 1) ? (float*)d_ws : out;
  const int kseg = I_F / KS;

  hipLaunchKernelGGL(tropical_main, dim3(256 * KS), dim3(NTHR), 0, stream,
                     X, W, dst, kseg);
  if (KS > 1) {
    hipLaunchKernelGGL(tropical_reduce, dim3(BO / 4 / NTHR), dim3(NTHR), 0,
                       stream, (const float4*)d_ws, (float4*)out, KS);
  }
}

// Round 4
// 20.953 us; speedup vs baseline: 2.4822x; 1.4839x over previous
//
#include <hip/hip_runtime.h>
#include <math.h>

// Tropical (min-plus) linear: out[b,o] = min_i(X[b,i] + W[o,i])
// B=1024, I=512, O=512 fp32. Pure-VALU problem (no min-plus MFMA).
//
// Round-4 design: K-ON-LANES.
//  - lane = (og[2] , k16[4]): k-position = k16, o-subgroup = og.
//  - Per thread: acc[m][n] partial mins for 8 b-rows x 4 o-cols, over the
//    lane's k-slice. Both X and W are PER-LANE coalesced global loads
//    (L2-resident: X+W = 3 MB). No LDS, no barriers, no broadcast operand,
//    no K-split (K collapses inside the wave) -> one kernel, no workspace.
//  - Per 64-k chunk per thread: 8 X + 4 W b128 loads feed 192 VALU
//    (v_add + v_min3), 64 independent acc chains -> latency-tolerant.
//  - Final: 4-step compacting butterfly min-reduce over lane bits 0..3
//    (the k16 dim); lane ends with 2 finished outputs, stores them.
//  - Wave tile 8b x 16o; block = 4 waves = 16b x 32o; grid 1024 blocks,
//    XCD-swizzled so blocks sharing a W-panel land on the same XCD's L2.

#define B_SZ  1024
#define O_F   512
#define I_F   512
#define MB    8      // b rows per wave
#define NO    4      // o per thread (wave covers NO*4 = 16 o)
#define NTHR  256

__global__ __launch_bounds__(NTHR, 4)
void tropical_klane(const float* __restrict__ X,
                    const float* __restrict__ W,
                    float* __restrict__ out) {
  const int tid  = threadIdx.x;
  const int wv   = tid >> 6;
  const int lane = tid & 63;
  const int k16  = lane & 15;   // k position within 16-lane group
  const int og   = lane >> 4;   // o subgroup 0..3

  // Block tile: 16 b x 32 o. b-tile varies fastest within an XCD so the
  // 8 consecutive same-XCD blocks share one W panel in that XCD's L2.
  const int bid = blockIdx.x;
  const int swz = (bid & 7) * 128 + (bid >> 3);   // bijective, 1024 % 8 == 0
  const int ot  = swz >> 6;                       // 16 o-tiles of 32
  const int bt  = swz & 63;                       // 64 b-tiles of 16
  const int b0  = bt * 16 + (wv >> 1) * MB;
  const int o0  = ot * 32 + (wv & 1) * 16;

  const float4* __restrict__ Xv = reinterpret_cast<const float4*>(X);
  const float4* __restrict__ Wv = reinterpret_cast<const float4*>(W);
  const int R4 = I_F / 4;   // 128 float4 per row

  float acc[MB][NO];
#pragma unroll
  for (int m = 0; m < MB; ++m)
#pragma unroll
    for (int n = 0; n < NO; ++n) acc[m][n] = __builtin_inff();

#pragma unroll
  for (int c = 0; c < I_F / 64; ++c) {          // 8 chunks of 64 k
    const int k4 = c * 16 + k16;                // float4 col index
    float4 x4[MB];
#pragma unroll
    for (int m = 0; m < MB; ++m)
      x4[m] = Xv[(size_t)(b0 + m) * R4 + k4];   // 4-way redundant across og,
                                                // coalesced within k16 group
#pragma unroll
    for (int n = 0; n < NO; ++n) {
      const float4 w4 = Wv[(size_t)(o0 + n * 4 + og) * R4 + k4];
#pragma unroll
      for (int m = 0; m < MB; ++m) {
        float c0 = x4[m].x + w4.x;
        float c1 = x4[m].y + w4.y;
        float c2 = x4[m].z + w4.z;
        float c3 = x4[m].w + w4.w;
        acc[m][n] = fminf(fminf(c0, c1), acc[m][n]);   // v_min3_f32
        acc[m][n] = fminf(fminf(c2, c3), acc[m][n]);   // v_min3_f32
      }
    }
  }

  // ---- butterfly min-reduce over lane bits 0..3 (k16), compacting ----
  // items j = (m<<2)|n ; step s fixes j-bit s == lane-bit s.
  float v0[32];
#pragma unroll
  for (int m = 0; m < MB; ++m)
#pragma unroll
    for (int n = 0; n < NO; ++n) v0[(m << 2) | n] = acc[m][n];

  const bool bb0 = (k16 & 1);
  float v1[16];
#pragma unroll
  for (int i = 0; i < 16; ++i) {
    float keep = bb0 ? v0[2 * i + 1] : v0[2 * i];
    float send = bb0 ? v0[2 * i]     : v0[2 * i + 1];
    v1[i] = fminf(keep, __shfl_xor(send, 1, 64));
  }
  const bool bb1 = (k16 >> 1) & 1;
  float v2[8];
#pragma unroll
  for (int i = 0; i < 8; ++i) {
    float keep = bb1 ? v1[2 * i + 1] : v1[2 * i];
    float send = bb1 ? v1[2 * i]     : v1[2 * i + 1];
    v2[i] = fminf(keep, __shfl_xor(send, 2, 64));
  }
  const bool bb2 = (k16 >> 2) & 1;
  float v3[4];
#pragma unroll
  for (int i = 0; i < 4; ++i) {
    float keep = bb2 ? v2[2 * i + 1] : v2[2 * i];
    float send = bb2 ? v2[2 * i]     : v2[2 * i + 1];
    v3[i] = fminf(keep, __shfl_xor(send, 4, 64));
  }
  const bool bb3 = (k16 >> 3) & 1;
  float v4[2];
#pragma unroll
  for (int i = 0; i < 2; ++i) {
    float keep = bb3 ? v3[2 * i + 1] : v3[2 * i];
    float send = bb3 ? v3[2 * i]     : v3[2 * i + 1];
    v4[i] = fminf(keep, __shfl_xor(send, 8, 64));
  }

  // lane holds items j = k16 + 16*h  ->  m = (k16>>2) + 4h, n = k16&3
  const int mrow = k16 >> 2;
  const int ncol = k16 & 3;
#pragma unroll
  for (int h = 0; h < 2; ++h) {
    out[(size_t)(b0 + 4 * h + mrow) * O_F + o0 + 4 * ncol + og] = v4[h];
  }
}

extern "C" void kernel_launch(void* const* d_in, const int* in_sizes, int n_in,
                              void* d_out, int out_size, void* d_ws, size_t ws_size,
                              hipStream_t stream) {
  const float* X = (const float*)d_in[0];
  const float* W = (const float*)d_in[1];
  float* out     = (float*)d_out;

  hipLaunchKernelGGL(tropical_klane, dim3(1024), dim3(NTHR), 0, stream,
                     X, W, out);
}

// Round 5
// 17.963 us; speedup vs baseline: 2.8954x; 1.1665x over previous
//
#include <hip/hip_runtime.h>
#include <math.h>

// Tropical (min-plus) linear: out[b,o] = min_i(X[b,i] + W[o,i])
// B=1024, I=512, O=512 fp32. Pure-VALU problem (no min-plus MFMA).
//
// Round-5: K-on-lanes + SPLIT OPERAND PIPES.
//  - X block tile (16 b x 512 k = 32 KB) staged in LDS ONCE via
//    global_load_lds (linear layout, one barrier in the whole kernel).
//    Main-loop X reads are ds_read_b128 on the lgkm pipe: 16 unique
//    16B-consecutive addresses x 4-way broadcast -> conflict-free.
//  - W streams from L1 on the vm pipe, per-lane coalesced, all-unique
//    (lane quad-groups read 4 distinct o-rows).
//  - Per thread per 4k: 8 LDS + 4 L1 b128 insts feed 192 VALU
//    (v_add_f32 + v_min3_f32). Per CU per 4k: VALU 1536 SIMD-cyc >
//    L1 ~1024 cyc > LDS ~1024 cyc -> VALU-bound by design.
//  - lane = (og[2], k16[4]); per-thread acc 8b x 4o; 4-step compacting
//    butterfly min over k16 bits finishes the k-reduction in-wave.
//  - Grid 1024 blocks (16 b-rows x 32 o-cols each), XCD-swizzled.

#define B_SZ  1024
#define O_F   512
#define I_F   512
#define MB    8      // b rows per thread (and per wave)
#define NO    4      // o per thread (wave covers 16 o)
#define NTHR  256

typedef __attribute__((ext_vector_type(4))) float f32x4;

__global__ __launch_bounds__(NTHR, 4)
void tropical_v5(const float* __restrict__ X,
                 const float* __restrict__ W,
                 float* __restrict__ out) {
  __shared__ f32x4 Xs[16 * 128];   // 32 KB: [b(16)][k4(128)] linear

  const int tid  = threadIdx.x;
  const int wv   = tid >> 6;
  const int lane = tid & 63;
  const int k16  = lane & 15;   // k4 position within 16-lane group
  const int og   = lane >> 4;   // o subgroup 0..3

  // Block tile: 16 b x 32 o; b varies fastest within an XCD (W-panel L2 reuse).
  const int bid = blockIdx.x;
  const int swz = (bid & 7) * 128 + (bid >> 3);   // bijective, 1024 % 8 == 0
  const int ot  = swz >> 6;                       // 16 o-tiles of 32
  const int bt  = swz & 63;                       // 64 b-tiles of 16
  const int b0b = bt * 16;                        // block b base
  const int o0  = ot * 32 + (wv & 1) * 16;        // wave o base
  const int bw  = (wv >> 1) * 8;                  // wave b offset in tile

  const f32x4* __restrict__ Xv = reinterpret_cast<const f32x4*>(X);
  const f32x4* __restrict__ Wv = reinterpret_cast<const f32x4*>(W);
  const int R4 = I_F / 4;   // 128 float4 per row

  // ---- stage X tile once: 2048 float4 = 8 rounds x 256 lanes ----
#pragma unroll
  for (int it = 0; it < 8; ++it) {
    const int slot0 = (wv * 8 + it) * 64;          // wave-uniform LDS slot
    const int f     = slot0 + lane;                // 0..2047
    const f32x4* src = &Xv[(size_t)(b0b + (f >> 7)) * R4 + (f & 127)];
    __builtin_amdgcn_global_load_lds(
        (const __attribute__((address_space(1))) void*)src,
        (__attribute__((address_space(3))) void*)&Xs[slot0],
        16, 0, 0);
  }
  __syncthreads();   // drains vmcnt; only barrier in the kernel

  float acc[MB][NO];
#pragma unroll
  for (int m = 0; m < MB; ++m)
#pragma unroll
    for (int n = 0; n < NO; ++n) acc[m][n] = __builtin_inff();

#pragma unroll
  for (int c = 0; c < I_F / 64; ++c) {             // 8 chunks of 64 k
    const int k4 = c * 16 + k16;
    f32x4 x4[MB];
#pragma unroll
    for (int m = 0; m < MB; ++m)
      x4[m] = Xs[(bw + m) * 128 + k4];             // ds_read_b128, no conflict
#pragma unroll
    for (int n = 0; n < NO; ++n) {
      const f32x4 w4 = Wv[(size_t)(o0 + n * 4 + og) * R4 + k4];  // L1, unique
#pragma unroll
      for (int m = 0; m < MB; ++m) {
        float c0 = x4[m].x + w4.x;
        float c1 = x4[m].y + w4.y;
        float c2 = x4[m].z + w4.z;
        float c3 = x4[m].w + w4.w;
        acc[m][n] = fminf(fminf(c0, c1), acc[m][n]);   // v_min3_f32
        acc[m][n] = fminf(fminf(c2, c3), acc[m][n]);   // v_min3_f32
      }
    }
  }

  // ---- compacting butterfly min-reduce over lane bits 0..3 (k16) ----
  float v0[32];
#pragma unroll
  for (int m = 0; m < MB; ++m)
#pragma unroll
    for (int n = 0; n < NO; ++n) v0[(m << 2) | n] = acc[m][n];

  const bool bb0 = (k16 & 1);
  float v1[16];
#pragma unroll
  for (int i = 0; i < 16; ++i) {
    float keep = bb0 ? v0[2 * i + 1] : v0[2 * i];
    float send = bb0 ? v0[2 * i]     : v0[2 * i + 1];
    v1[i] = fminf(keep, __shfl_xor(send, 1, 64));
  }
  const bool bb1 = (k16 >> 1) & 1;
  float v2[8];
#pragma unroll
  for (int i = 0; i < 8; ++i) {
    float keep = bb1 ? v1[2 * i + 1] : v1[2 * i];
    float send = bb1 ? v1[2 * i]     : v1[2 * i + 1];
    v2[i] = fminf(keep, __shfl_xor(send, 2, 64));
  }
  const bool bb2 = (k16 >> 2) & 1;
  float v3[4];
#pragma unroll
  for (int i = 0; i < 4; ++i) {
    float keep = bb2 ? v2[2 * i + 1] : v2[2 * i];
    float send = bb2 ? v2[2 * i]     : v2[2 * i + 1];
    v3[i] = fminf(keep, __shfl_xor(send, 4, 64));
  }
  const bool bb3 = (k16 >> 3) & 1;
  float v4[2];
#pragma unroll
  for (int i = 0; i < 2; ++i) {
    float keep = bb3 ? v3[2 * i + 1] : v3[2 * i];
    float send = bb3 ? v3[2 * i]     : v3[2 * i + 1];
    v4[i] = fminf(keep, __shfl_xor(send, 8, 64));
  }

  // lane holds items j = k16 + 16*h  ->  m = (k16>>2) + 4h, n = k16&3
  const int mrow = k16 >> 2;
  const int ncol = k16 & 3;
#pragma unroll
  for (int h = 0; h < 2; ++h) {
    out[(size_t)(b0b + bw + 4 * h + mrow) * O_F + o0 + 4 * ncol + og] = v4[h];
  }
}

extern "C" void kernel_launch(void* const* d_in, const int* in_sizes, int n_in,
                              void* d_out, int out_size, void* d_ws, size_t ws_size,
                              hipStream_t stream) {
  const float* X = (const float*)d_in[0];
  const float* W = (const float*)d_in[1];
  float* out     = (float*)d_out;

  hipLaunchKernelGGL(tropical_v5, dim3(1024), dim3(NTHR), 0, stream,
                     X, W, out);
}